// Round 4
// baseline (263.328 us; speedup 1.0000x reference)
//
#include <hip/hip_runtime.h>
#include <math.h>

// Problem constants (fixed by setup_inputs): x is (8,1024,1024,2) fp32, k=61
#define NB 8
#define HH 1024
#define WW 1024
#define RAD 30
#define KS 61
#define ROWSZ 2048             /* floats per row (1024 pixels x 2ch) */
#define IMGSZ (HH * ROWSZ)
#define STR4 512               /* float4 per row */
#define NCOL4 (NB * STR4)      /* 4096 float4 columns */
#define VSEGH 32
#define VNSEG (HH / VSEGH)     /* 32 */
#define EPSV 1e-7f
#define SCALEV (1.0f / (float)(KS * KS * 2))
#define PDW (WW + WW / 8)
#define PD(i) ((i) + ((i) >> 3))

__device__ __forceinline__ float4 f4add(float4 a, float4 b) {
    return make_float4(a.x + b.x, a.y + b.y, a.z + b.z, a.w + b.w);
}
__device__ __forceinline__ float4 f4sub(float4 a, float4 b) {
    return make_float4(a.x - b.x, a.y - b.y, a.z - b.z, a.w - b.w);
}

// ---------------------------------------------------------------------------
// K1: vertical 61-tap box-sum of x -> V1. Software-pipelined interior path:
// prefetch next 4-row group (8 float4 loads) before consuming current.
// __launch_bounds__(256,2): grid 512 = 2 blocks/CU = 2 waves/EU, so allow up
// to ~256 VGPR for load batching.
__global__ __launch_bounds__(256, 2) void vbox_kernel(const float* __restrict__ in,
                                                      float* __restrict__ out) {
    int tid = blockIdx.x * 256 + threadIdx.x;
    int col = tid & (NCOL4 - 1);
    int seg = tid >> 12;
    int n = col >> 9;
    int w4 = col & (STR4 - 1);
    const float4* ip = (const float4*)(in + (size_t)n * IMGSZ) + w4;
    float4* op = (float4*)(out + (size_t)n * IMGSZ) + w4;
    int h0 = seg * VSEGH, hend = h0 + VSEGH;
    float4 S = make_float4(0.f, 0.f, 0.f, 0.f);
    int lo = h0 - RAD; if (lo < 0) lo = 0;
    int h = lo;
    for (; h + 4 <= h0 + RAD; h += 4) {
        float4 v0 = ip[(h + 0) * STR4];
        float4 v1 = ip[(h + 1) * STR4];
        float4 v2 = ip[(h + 2) * STR4];
        float4 v3 = ip[(h + 3) * STR4];
        S = f4add(S, f4add(f4add(v0, v1), f4add(v2, v3)));
    }
    for (; h < h0 + RAD; ++h) S = f4add(S, ip[h * STR4]);

    if (seg != 0 && seg != VNSEG - 1) {
        const float4* lp = ip + (h0 + RAD) * STR4;   // leading edge
        const float4* tp = ip + (h0 - RAD) * STR4;   // trailing edge
        float4* sp = op + h0 * STR4;
        float4 A[4], B[4];
        #pragma unroll
        for (int i = 0; i < 4; ++i) { A[i] = lp[i * STR4]; B[i] = tp[i * STR4]; }
        for (int ho = h0; ho < hend; ho += 4) {
            int noff = (ho + 4 < hend) ? (ho + 4 - h0) * STR4 : 0;
            float4 An[4], Bn[4];
            #pragma unroll
            for (int i = 0; i < 4; ++i) { An[i] = lp[noff + i * STR4]; Bn[i] = tp[noff + i * STR4]; }
            #pragma unroll
            for (int i = 0; i < 4; ++i) {
                S = f4add(S, A[i]);
                sp[(ho - h0 + i) * STR4] = S;
                S = f4sub(S, B[i]);
            }
            #pragma unroll
            for (int i = 0; i < 4; ++i) { A[i] = An[i]; B[i] = Bn[i]; }
        }
    } else {
        const float4 Z = make_float4(0.f, 0.f, 0.f, 0.f);
        for (int ho = h0; ho < hend; ho += 4) {
            float4 a[4], b[4];
            #pragma unroll
            for (int i = 0; i < 4; ++i) {
                int ha = ho + i + RAD;
                a[i] = (ha < HH) ? ip[ha * STR4] : Z;
            }
            #pragma unroll
            for (int i = 0; i < 4; ++i) {
                int hb = ho + i - RAD;
                b[i] = (hb >= 0) ? ip[hb * STR4] : Z;
            }
            #pragma unroll
            for (int i = 0; i < 4; ++i) {
                S = f4add(S, a[i]);
                op[(ho + i) * STR4] = S;
                S = f4sub(S, b[i]);
            }
        }
    }
}

__device__ inline float wave_incl_scan(float v) {
    int lane = threadIdx.x & 63;
    #pragma unroll
    for (int d = 1; d < 64; d <<= 1) {
        float o = __shfl_up(v, d, 64);
        if (lane >= d) v += o;
    }
    return v;
}

// ---------------------------------------------------------------------------
// K2: per row -- out = x - s*H(V1); then q1 = H(out), q2 = H(out^2) computed
// in-row (prefix sums) and written. q1 overwrites V1 in place (row fully
// staged to LDS before; v1q1 passed WITHOUT restrict).
__global__ __launch_bounds__(256) void hboxq_kernel(float* v1q1,
                                                    const float* __restrict__ x,
                                                    float* __restrict__ outp,
                                                    float* __restrict__ q2) {
    __shared__ float ch[4][PDW];
    __shared__ float wtot[4];
    int t = threadIdx.x;
    int t2 = t + 256;
    size_t g = (size_t)blockIdx.x * ROWSZ;
    const float4* vrow = (const float4*)(v1q1 + g);
    const float4* xrow = (const float4*)(x + g);
    float4 va = vrow[t], vb = vrow[t2];
    float4 xa = xrow[t], xb = xrow[t2];
    ch[0][PD(2 * t)] = va.x;      ch[1][PD(2 * t)] = va.y;
    ch[0][PD(2 * t + 1)] = va.z;  ch[1][PD(2 * t + 1)] = va.w;
    ch[0][PD(2 * t2)] = vb.x;     ch[1][PD(2 * t2)] = vb.y;
    ch[0][PD(2 * t2 + 1)] = vb.z; ch[1][PD(2 * t2 + 1)] = vb.w;
    __syncthreads();
    // prefix ch[0..1]: 2 waves per channel, chunk 8
    {
        int c = t >> 7, j = t & 127, base = j * 8;
        float v[8]; float run = 0.f;
        #pragma unroll
        for (int i = 0; i < 8; ++i) { run += ch[c][PD(base + i)]; v[i] = run; }
        float incl = wave_incl_scan(run);
        int wid = t >> 6;
        if ((t & 63) == 63) wtot[wid] = incl;
        __syncthreads();
        float off = incl - run;
        if (wid & 1) off += wtot[wid - 1];
        #pragma unroll
        for (int i = 0; i < 8; ++i) ch[c][PD(base + i)] = off + v[i];
    }
    __syncthreads();
    // out = x - s*boxdiff
    float4 o0, o1;
    {
        int w0 = 2 * t, w1 = 2 * t + 1;
        int hi0 = w0 + RAD; if (hi0 > WW - 1) hi0 = WW - 1;
        int hi1 = w1 + RAD; if (hi1 > WW - 1) hi1 = WW - 1;
        int lo0 = w0 - RAD - 1, lo1 = w1 - RAD - 1;
        float s00 = ch[0][PD(hi0)], s10 = ch[1][PD(hi0)];
        if (lo0 >= 0) { s00 -= ch[0][PD(lo0)]; s10 -= ch[1][PD(lo0)]; }
        float s01 = ch[0][PD(hi1)], s11 = ch[1][PD(hi1)];
        if (lo1 >= 0) { s01 -= ch[0][PD(lo1)]; s11 -= ch[1][PD(lo1)]; }
        o0 = make_float4(xa.x - SCALEV * s00, xa.y - SCALEV * s10,
                         xa.z - SCALEV * s01, xa.w - SCALEV * s11);
        w0 = 2 * t2; w1 = 2 * t2 + 1;
        hi0 = w0 + RAD; if (hi0 > WW - 1) hi0 = WW - 1;
        hi1 = w1 + RAD; if (hi1 > WW - 1) hi1 = WW - 1;
        lo0 = w0 - RAD - 1; lo1 = w1 - RAD - 1;
        s00 = ch[0][PD(hi0)]; s10 = ch[1][PD(hi0)];
        if (lo0 >= 0) { s00 -= ch[0][PD(lo0)]; s10 -= ch[1][PD(lo0)]; }
        s01 = ch[0][PD(hi1)]; s11 = ch[1][PD(hi1)];
        if (lo1 >= 0) { s01 -= ch[0][PD(lo1)]; s11 -= ch[1][PD(lo1)]; }
        o1 = make_float4(xb.x - SCALEV * s00, xb.y - SCALEV * s10,
                         xb.z - SCALEV * s01, xb.w - SCALEV * s11);
    }
    float4* orow = (float4*)(outp + g);
    orow[t] = o0; orow[t2] = o1;
    __syncthreads();   // all prefix reads done before overwrite
    // stash out (ch0,ch1) and out^2 (ch2,ch3), deinterleaved
    ch[0][PD(2 * t)] = o0.x;          ch[1][PD(2 * t)] = o0.y;
    ch[0][PD(2 * t + 1)] = o0.z;      ch[1][PD(2 * t + 1)] = o0.w;
    ch[2][PD(2 * t)] = o0.x * o0.x;   ch[3][PD(2 * t)] = o0.y * o0.y;
    ch[2][PD(2 * t + 1)] = o0.z * o0.z; ch[3][PD(2 * t + 1)] = o0.w * o0.w;
    ch[0][PD(2 * t2)] = o1.x;         ch[1][PD(2 * t2)] = o1.y;
    ch[0][PD(2 * t2 + 1)] = o1.z;     ch[1][PD(2 * t2 + 1)] = o1.w;
    ch[2][PD(2 * t2)] = o1.x * o1.x;  ch[3][PD(2 * t2)] = o1.y * o1.y;
    ch[2][PD(2 * t2 + 1)] = o1.z * o1.z; ch[3][PD(2 * t2 + 1)] = o1.w * o1.w;
    __syncthreads();
    // prefix 4 arrays, 1 wave each, chunk 16
    {
        int a = t >> 6, j = t & 63, base = j * 16;
        float v[16]; float run = 0.f;
        #pragma unroll
        for (int i = 0; i < 16; ++i) { run += ch[a][PD(base + i)]; v[i] = run; }
        float incl = wave_incl_scan(run);
        float off = incl - run;
        #pragma unroll
        for (int i = 0; i < 16; ++i) ch[a][PD(base + i)] = off + v[i];
    }
    __syncthreads();
    // q1 = H(out), q2 = H(out^2) (raw horizontal sums, scale applied in K3)
    float4* q1row = (float4*)(v1q1 + g);
    float4* q2row = (float4*)(q2 + g);
    #pragma unroll
    for (int k = 0; k < 2; ++k) {
        int jj = (k == 0) ? t : t2;
        int w0 = 2 * jj, w1 = 2 * jj + 1;
        int hi0 = w0 + RAD; if (hi0 > WW - 1) hi0 = WW - 1;
        int hi1 = w1 + RAD; if (hi1 > WW - 1) hi1 = WW - 1;
        int lo0 = w0 - RAD - 1, lo1 = w1 - RAD - 1;
        float a0 = ch[0][PD(hi0)], b0 = ch[1][PD(hi0)];
        float c0 = ch[2][PD(hi0)], d0 = ch[3][PD(hi0)];
        if (lo0 >= 0) {
            a0 -= ch[0][PD(lo0)]; b0 -= ch[1][PD(lo0)];
            c0 -= ch[2][PD(lo0)]; d0 -= ch[3][PD(lo0)];
        }
        float a1 = ch[0][PD(hi1)], b1 = ch[1][PD(hi1)];
        float c1v = ch[2][PD(hi1)], d1 = ch[3][PD(hi1)];
        if (lo1 >= 0) {
            a1 -= ch[0][PD(lo1)]; b1 -= ch[1][PD(lo1)];
            c1v -= ch[2][PD(lo1)]; d1 -= ch[3][PD(lo1)];
        }
        q1row[jj] = make_float4(a0, b0, a1, b1);
        q2row[jj] = make_float4(c0, d0, c1v, d1);
    }
}

// ---------------------------------------------------------------------------
// K3: vertical 61-tap sliding window over q1,q2 + finalize y = out/std,
// in place on d_out. Software-pipelined (depth 2, 10 loads per group).
__device__ __forceinline__ float4 fin4(float4 S1, float4 S2, float4 O) {
    float4 r;
    float c1, var;
    c1 = SCALEV * S1.x; var = SCALEV * S2.x - c1 * c1;
    r.x = O.x / (sqrtf(fmaxf(var, 0.f)) + EPSV);
    c1 = SCALEV * S1.y; var = SCALEV * S2.y - c1 * c1;
    r.y = O.y / (sqrtf(fmaxf(var, 0.f)) + EPSV);
    c1 = SCALEV * S1.z; var = SCALEV * S2.z - c1 * c1;
    r.z = O.z / (sqrtf(fmaxf(var, 0.f)) + EPSV);
    c1 = SCALEV * S1.w; var = SCALEV * S2.w - c1 * c1;
    r.w = O.w / (sqrtf(fmaxf(var, 0.f)) + EPSV);
    return r;
}

__global__ __launch_bounds__(256, 2) void vfin_kernel(const float* __restrict__ q1g,
                                                      const float* __restrict__ q2g,
                                                      float* __restrict__ outg) {
    int tid = blockIdx.x * 256 + threadIdx.x;
    int col = tid & (NCOL4 - 1);
    int seg = tid >> 12;
    int n = col >> 9;
    int w4 = col & (STR4 - 1);
    const float4* p1 = (const float4*)(q1g + (size_t)n * IMGSZ) + w4;
    const float4* p2 = (const float4*)(q2g + (size_t)n * IMGSZ) + w4;
    float4* po = (float4*)(outg + (size_t)n * IMGSZ) + w4;
    int h0 = seg * VSEGH, hend = h0 + VSEGH;
    float4 S1 = make_float4(0.f, 0.f, 0.f, 0.f);
    float4 S2 = make_float4(0.f, 0.f, 0.f, 0.f);
    int lo = h0 - RAD; if (lo < 0) lo = 0;
    int h = lo;
    for (; h + 2 <= h0 + RAD; h += 2) {
        float4 a0 = p1[(h + 0) * STR4], a1 = p1[(h + 1) * STR4];
        float4 b0 = p2[(h + 0) * STR4], b1 = p2[(h + 1) * STR4];
        S1 = f4add(S1, f4add(a0, a1));
        S2 = f4add(S2, f4add(b0, b1));
    }
    for (; h < h0 + RAD; ++h) {
        S1 = f4add(S1, p1[h * STR4]);
        S2 = f4add(S2, p2[h * STR4]);
    }

    if (seg != 0 && seg != VNSEG - 1) {
        const float4* lp1 = p1 + (h0 + RAD) * STR4;
        const float4* tp1 = p1 + (h0 - RAD) * STR4;
        const float4* lp2 = p2 + (h0 + RAD) * STR4;
        const float4* tp2 = p2 + (h0 - RAD) * STR4;
        float4* cp = po + h0 * STR4;
        float4 L1[2], L2[2], T1[2], T2[2], O[2];
        #pragma unroll
        for (int i = 0; i < 2; ++i) {
            L1[i] = lp1[i * STR4]; L2[i] = lp2[i * STR4];
            T1[i] = tp1[i * STR4]; T2[i] = tp2[i * STR4];
            O[i] = cp[i * STR4];
        }
        for (int ho = h0; ho < hend; ho += 2) {
            int noff = (ho + 2 < hend) ? (ho + 2 - h0) * STR4 : 0;
            float4 L1n[2], L2n[2], T1n[2], T2n[2], On[2];
            #pragma unroll
            for (int i = 0; i < 2; ++i) {
                L1n[i] = lp1[noff + i * STR4]; L2n[i] = lp2[noff + i * STR4];
                T1n[i] = tp1[noff + i * STR4]; T2n[i] = tp2[noff + i * STR4];
                On[i] = cp[noff + i * STR4];
            }
            #pragma unroll
            for (int i = 0; i < 2; ++i) {
                S1 = f4add(S1, L1[i]); S2 = f4add(S2, L2[i]);
                cp[(ho - h0 + i) * STR4] = fin4(S1, S2, O[i]);
                S1 = f4sub(S1, T1[i]); S2 = f4sub(S2, T2[i]);
            }
            #pragma unroll
            for (int i = 0; i < 2; ++i) {
                L1[i] = L1n[i]; L2[i] = L2n[i];
                T1[i] = T1n[i]; T2[i] = T2n[i]; O[i] = On[i];
            }
        }
    } else {
        const float4 Z = make_float4(0.f, 0.f, 0.f, 0.f);
        for (int ho = h0; ho < hend; ho += 2) {
            float4 a1[2], a2[2], b1[2], b2[2], O[2];
            #pragma unroll
            for (int i = 0; i < 2; ++i) {
                int ha = ho + i + RAD;
                a1[i] = (ha < HH) ? p1[ha * STR4] : Z;
                a2[i] = (ha < HH) ? p2[ha * STR4] : Z;
                O[i] = po[(ho + i) * STR4];
            }
            #pragma unroll
            for (int i = 0; i < 2; ++i) {
                int hb = ho + i - RAD;
                b1[i] = (hb >= 0) ? p1[hb * STR4] : Z;
                b2[i] = (hb >= 0) ? p2[hb * STR4] : Z;
            }
            #pragma unroll
            for (int i = 0; i < 2; ++i) {
                S1 = f4add(S1, a1[i]); S2 = f4add(S2, a2[i]);
                po[(ho + i) * STR4] = fin4(S1, S2, O[i]);
                S1 = f4sub(S1, b1[i]); S2 = f4sub(S2, b2[i]);
            }
        }
    }
}

extern "C" void kernel_launch(void* const* d_in, const int* in_sizes, int n_in,
                              void* d_out, int out_size, void* d_ws, size_t ws_size,
                              hipStream_t stream) {
    const float* x = (const float*)d_in[0];
    float* out = (float*)d_out;
    float* V1 = (float*)d_ws;                     // 64 MB: vbox(x), reused as q1
    float* Q2 = V1 + (size_t)NB * IMGSZ;          // 64 MB: q2 = H(out^2)

    vbox_kernel<<<(NCOL4 * VNSEG) / 256, 256, 0, stream>>>(x, V1);
    hboxq_kernel<<<NB * HH, 256, 0, stream>>>(V1, x, out, Q2);
    vfin_kernel<<<(NCOL4 * VNSEG) / 256, 256, 0, stream>>>(V1, Q2, out);
}

// Round 5
// 218.952 us; speedup vs baseline: 1.2027x; 1.2027x over previous
//
#include <hip/hip_runtime.h>
#include <math.h>

// Problem constants (fixed by setup_inputs): x is (8,1024,1024,2) fp32, k=61
#define NB 8
#define HH 1024
#define WW 1024
#define RAD 30
#define KS 61
#define ROWSZ 2048             /* floats per row (1024 px x 2 ch) */
#define IMGSZ (HH * ROWSZ)
#define STR2 1024              /* float2 per row */
#define NCOL2 (NB * STR2)      /* 8192 float2 columns */
#define VSEGH 32
#define VNSEG (HH / VSEGH)     /* 32 */
#define EPSV 1e-7f
#define SCALEV (1.0f / (float)(KS * KS * 2))
#define PDW (WW + WW / 8)
#define PD(i) ((i) + ((i) >> 3))

// ---- bf16 pack/unpack (manual, round-to-nearest-even) ----------------------
__device__ __forceinline__ unsigned bf16_rn(float f) {
    unsigned u = __float_as_uint(f);
    return (u + 0x7FFFu + ((u >> 16) & 1u)) >> 16;
}
__device__ __forceinline__ unsigned pk2(float a, float b) {
    return bf16_rn(a) | (bf16_rn(b) << 16);
}
__device__ __forceinline__ float2 up2(unsigned u) {
    return make_float2(__uint_as_float(u << 16),
                       __uint_as_float(u & 0xFFFF0000u));
}

__device__ __forceinline__ float2 f2add(float2 a, float2 b) {
    return make_float2(a.x + b.x, a.y + b.y);
}
__device__ __forceinline__ float2 f2sub(float2 a, float2 b) {
    return make_float2(a.x - b.x, a.y - b.y);
}

// ---------------------------------------------------------------------------
// K1: vertical 61-tap box-sum of x -> V1 (bf16-packed). float2 columns,
// 1024 blocks (4/CU, 16 waves/CU) for TLP; unroll-8 batched loads for ILP.
__global__ __launch_bounds__(256, 4) void vbox_kernel(const float* __restrict__ in,
                                                      unsigned* __restrict__ out) {
    int tid = blockIdx.x * 256 + threadIdx.x;
    int col = tid & (NCOL2 - 1);
    int seg = tid >> 13;
    int n = col >> 10;
    int w2 = col & (STR2 - 1);
    const float2* ip = (const float2*)(in + (size_t)n * IMGSZ) + w2;
    unsigned* op = out + (size_t)n * (IMGSZ / 2) + w2;
    int h0 = seg * VSEGH;
    float2 S = make_float2(0.f, 0.f);
    int lo = h0 - RAD; if (lo < 0) lo = 0;
    int h = lo;
    for (; h + 4 <= h0 + RAD; h += 4) {
        float2 v0 = ip[(h + 0) * STR2];
        float2 v1 = ip[(h + 1) * STR2];
        float2 v2 = ip[(h + 2) * STR2];
        float2 v3 = ip[(h + 3) * STR2];
        S = f2add(S, f2add(f2add(v0, v1), f2add(v2, v3)));
    }
    for (; h < h0 + RAD; ++h) S = f2add(S, ip[h * STR2]);

    if (seg != 0 && seg != VNSEG - 1) {
        const float2* lp = ip + (h0 + RAD) * STR2;
        const float2* tp = ip + (h0 - RAD) * STR2;
        unsigned* opp = op + (size_t)h0 * STR2;
        for (int r = 0; r < VSEGH; r += 8) {
            float2 L[8], T[8];
            #pragma unroll
            for (int i = 0; i < 8; ++i) L[i] = lp[(r + i) * STR2];
            #pragma unroll
            for (int i = 0; i < 8; ++i) T[i] = tp[(r + i) * STR2];
            #pragma unroll
            for (int i = 0; i < 8; ++i) {
                S = f2add(S, L[i]);
                opp[(r + i) * STR2] = pk2(S.x, S.y);
                S = f2sub(S, T[i]);
            }
        }
    } else {
        const float2 Z = make_float2(0.f, 0.f);
        for (int ho = h0; ho < h0 + VSEGH; ho += 4) {
            float2 a[4], b[4];
            #pragma unroll
            for (int i = 0; i < 4; ++i) {
                int ha = ho + i + RAD;
                a[i] = (ha < HH) ? ip[ha * STR2] : Z;
            }
            #pragma unroll
            for (int i = 0; i < 4; ++i) {
                int hb = ho + i - RAD;
                b[i] = (hb >= 0) ? ip[hb * STR2] : Z;
            }
            #pragma unroll
            for (int i = 0; i < 4; ++i) {
                S = f2add(S, a[i]);
                op[(size_t)(ho + i) * STR2] = pk2(S.x, S.y);
                S = f2sub(S, b[i]);
            }
        }
    }
}

// ---------------------------------------------------------------------------
// K3: vertical dual box-sum of out and out^2 -> Z1, Z2 (bf16-packed).
__global__ __launch_bounds__(256, 4) void vbox2_kernel(const float* __restrict__ in,
                                                       unsigned* __restrict__ o1,
                                                       unsigned* __restrict__ o2) {
    int tid = blockIdx.x * 256 + threadIdx.x;
    int col = tid & (NCOL2 - 1);
    int seg = tid >> 13;
    int n = col >> 10;
    int w2 = col & (STR2 - 1);
    const float2* ip = (const float2*)(in + (size_t)n * IMGSZ) + w2;
    unsigned* p1 = o1 + (size_t)n * (IMGSZ / 2) + w2;
    unsigned* p2 = o2 + (size_t)n * (IMGSZ / 2) + w2;
    int h0 = seg * VSEGH;
    float2 S = make_float2(0.f, 0.f);
    float2 Q = make_float2(0.f, 0.f);
    int lo = h0 - RAD; if (lo < 0) lo = 0;
    int h = lo;
    for (; h + 4 <= h0 + RAD; h += 4) {
        float2 v0 = ip[(h + 0) * STR2];
        float2 v1 = ip[(h + 1) * STR2];
        float2 v2 = ip[(h + 2) * STR2];
        float2 v3 = ip[(h + 3) * STR2];
        S = f2add(S, f2add(f2add(v0, v1), f2add(v2, v3)));
        Q.x = fmaf(v0.x, v0.x, fmaf(v1.x, v1.x, fmaf(v2.x, v2.x, fmaf(v3.x, v3.x, Q.x))));
        Q.y = fmaf(v0.y, v0.y, fmaf(v1.y, v1.y, fmaf(v2.y, v2.y, fmaf(v3.y, v3.y, Q.y))));
    }
    for (; h < h0 + RAD; ++h) {
        float2 v = ip[h * STR2];
        S = f2add(S, v);
        Q.x = fmaf(v.x, v.x, Q.x); Q.y = fmaf(v.y, v.y, Q.y);
    }

    if (seg != 0 && seg != VNSEG - 1) {
        const float2* lp = ip + (h0 + RAD) * STR2;
        const float2* tp = ip + (h0 - RAD) * STR2;
        unsigned* q1 = p1 + (size_t)h0 * STR2;
        unsigned* q2 = p2 + (size_t)h0 * STR2;
        for (int r = 0; r < VSEGH; r += 8) {
            float2 L[8], T[8];
            #pragma unroll
            for (int i = 0; i < 8; ++i) L[i] = lp[(r + i) * STR2];
            #pragma unroll
            for (int i = 0; i < 8; ++i) T[i] = tp[(r + i) * STR2];
            #pragma unroll
            for (int i = 0; i < 8; ++i) {
                S = f2add(S, L[i]);
                Q.x = fmaf(L[i].x, L[i].x, Q.x);
                Q.y = fmaf(L[i].y, L[i].y, Q.y);
                q1[(r + i) * STR2] = pk2(S.x, S.y);
                q2[(r + i) * STR2] = pk2(Q.x, Q.y);
                S = f2sub(S, T[i]);
                Q.x = fmaf(-T[i].x, T[i].x, Q.x);
                Q.y = fmaf(-T[i].y, T[i].y, Q.y);
            }
        }
    } else {
        const float2 Z = make_float2(0.f, 0.f);
        for (int ho = h0; ho < h0 + VSEGH; ho += 4) {
            float2 a[4], b[4];
            #pragma unroll
            for (int i = 0; i < 4; ++i) {
                int ha = ho + i + RAD;
                a[i] = (ha < HH) ? ip[ha * STR2] : Z;
            }
            #pragma unroll
            for (int i = 0; i < 4; ++i) {
                int hb = ho + i - RAD;
                b[i] = (hb >= 0) ? ip[hb * STR2] : Z;
            }
            #pragma unroll
            for (int i = 0; i < 4; ++i) {
                S = f2add(S, a[i]);
                Q.x = fmaf(a[i].x, a[i].x, Q.x);
                Q.y = fmaf(a[i].y, a[i].y, Q.y);
                p1[(size_t)(ho + i) * STR2] = pk2(S.x, S.y);
                p2[(size_t)(ho + i) * STR2] = pk2(Q.x, Q.y);
                S = f2sub(S, b[i]);
                Q.x = fmaf(-b[i].x, b[i].x, Q.x);
                Q.y = fmaf(-b[i].y, b[i].y, Q.y);
            }
        }
    }
}

__device__ inline float wave_incl_scan(float v) {
    int lane = threadIdx.x & 63;
    #pragma unroll
    for (int d = 1; d < 64; d <<= 1) {
        float o = __shfl_up(v, d, 64);
        if (lane >= d) v += o;
    }
    return v;
}

// ---------------------------------------------------------------------------
// K2: horizontal box of V1 (bf16 in) per row + out = x - s*box. One block/row.
__global__ __launch_bounds__(256) void hbox_sub_kernel(const unsigned* __restrict__ vsum,
                                                       const float* __restrict__ x,
                                                       float* __restrict__ out) {
    __shared__ float ch[2][PDW];
    __shared__ float wtot[4];
    int t = threadIdx.x;
    size_t g = (size_t)blockIdx.x * ROWSZ;
    const uint4* vrow = (const uint4*)(vsum + (size_t)blockIdx.x * STR2);
    uint4 u = vrow[t];   // 4 pixels x 2 ch
    {
        float2 p0 = up2(u.x), p1 = up2(u.y), p2 = up2(u.z), p3 = up2(u.w);
        int w = 4 * t;
        ch[0][PD(w + 0)] = p0.x; ch[1][PD(w + 0)] = p0.y;
        ch[0][PD(w + 1)] = p1.x; ch[1][PD(w + 1)] = p1.y;
        ch[0][PD(w + 2)] = p2.x; ch[1][PD(w + 2)] = p2.y;
        ch[0][PD(w + 3)] = p3.x; ch[1][PD(w + 3)] = p3.y;
    }
    __syncthreads();
    // prefix: 2 waves per channel, per-thread chunk of 8
    {
        int c = t >> 7, j = t & 127, base = j * 8;
        float v[8]; float run = 0.f;
        #pragma unroll
        for (int i = 0; i < 8; ++i) { run += ch[c][PD(base + i)]; v[i] = run; }
        float incl = wave_incl_scan(run);
        int wid = t >> 6;
        if ((t & 63) == 63) wtot[wid] = incl;
        __syncthreads();
        float off = incl - run;
        if (wid & 1) off += wtot[wid - 1];
        #pragma unroll
        for (int i = 0; i < 8; ++i) ch[c][PD(base + i)] = off + v[i];
    }
    __syncthreads();
    const float4* xrow = (const float4*)(x + g);
    float4* orow = (float4*)(out + g);
    #pragma unroll
    for (int i = 0; i < 2; ++i) {
        int jj = t + 256 * i;
        int w0 = 2 * jj, w1 = 2 * jj + 1;
        int hi0 = w0 + RAD; if (hi0 > WW - 1) hi0 = WW - 1;
        int hi1 = w1 + RAD; if (hi1 > WW - 1) hi1 = WW - 1;
        int lo0 = w0 - RAD - 1, lo1 = w1 - RAD - 1;
        float s00 = ch[0][PD(hi0)], s10 = ch[1][PD(hi0)];
        if (lo0 >= 0) { s00 -= ch[0][PD(lo0)]; s10 -= ch[1][PD(lo0)]; }
        float s01 = ch[0][PD(hi1)], s11 = ch[1][PD(hi1)];
        if (lo1 >= 0) { s01 -= ch[0][PD(lo1)]; s11 -= ch[1][PD(lo1)]; }
        float4 xv = xrow[jj];
        float4 o;
        o.x = xv.x - SCALEV * s00; o.y = xv.y - SCALEV * s10;
        o.z = xv.z - SCALEV * s01; o.w = xv.w - SCALEV * s11;
        orow[jj] = o;
    }
}

// ---------------------------------------------------------------------------
// K4: horizontal box of Z1,Z2 (bf16 in) + finalize y = out/(sqrt(c2-c1^2)+eps).
__global__ __launch_bounds__(256) void hbox_final_kernel(const unsigned* __restrict__ z1,
                                                         const unsigned* __restrict__ z2,
                                                         float* __restrict__ out) {
    __shared__ float ch[4][PDW];
    int t = threadIdx.x;
    size_t g = (size_t)blockIdx.x * ROWSZ;
    const uint4* arow = (const uint4*)(z1 + (size_t)blockIdx.x * STR2);
    const uint4* brow = (const uint4*)(z2 + (size_t)blockIdx.x * STR2);
    uint4 ua = arow[t], ub = brow[t];
    {
        float2 p0 = up2(ua.x), p1 = up2(ua.y), p2 = up2(ua.z), p3 = up2(ua.w);
        float2 q0 = up2(ub.x), q1 = up2(ub.y), q2 = up2(ub.z), q3 = up2(ub.w);
        int w = 4 * t;
        ch[0][PD(w + 0)] = p0.x; ch[1][PD(w + 0)] = p0.y;
        ch[0][PD(w + 1)] = p1.x; ch[1][PD(w + 1)] = p1.y;
        ch[0][PD(w + 2)] = p2.x; ch[1][PD(w + 2)] = p2.y;
        ch[0][PD(w + 3)] = p3.x; ch[1][PD(w + 3)] = p3.y;
        ch[2][PD(w + 0)] = q0.x; ch[3][PD(w + 0)] = q0.y;
        ch[2][PD(w + 1)] = q1.x; ch[3][PD(w + 1)] = q1.y;
        ch[2][PD(w + 2)] = q2.x; ch[3][PD(w + 2)] = q2.y;
        ch[2][PD(w + 3)] = q3.x; ch[3][PD(w + 3)] = q3.y;
    }
    __syncthreads();
    // prefix: 4 arrays, 1 wave each, chunk 16
    {
        int a = t >> 6, j = t & 63, base = j * 16;
        float v[16]; float run = 0.f;
        #pragma unroll
        for (int i = 0; i < 16; ++i) { run += ch[a][PD(base + i)]; v[i] = run; }
        float incl = wave_incl_scan(run);
        float off = incl - run;
        #pragma unroll
        for (int i = 0; i < 16; ++i) ch[a][PD(base + i)] = off + v[i];
    }
    __syncthreads();
    float4* orow = (float4*)(out + g);
    #pragma unroll
    for (int i = 0; i < 2; ++i) {
        int jj = t + 256 * i;
        int w0 = 2 * jj, w1 = 2 * jj + 1;
        int hi0 = w0 + RAD; if (hi0 > WW - 1) hi0 = WW - 1;
        int hi1 = w1 + RAD; if (hi1 > WW - 1) hi1 = WW - 1;
        int lo0 = w0 - RAD - 1, lo1 = w1 - RAD - 1;
        float s1a = ch[0][PD(hi0)], s1b = ch[1][PD(hi0)];
        float s2a = ch[2][PD(hi0)], s2b = ch[3][PD(hi0)];
        if (lo0 >= 0) {
            s1a -= ch[0][PD(lo0)]; s1b -= ch[1][PD(lo0)];
            s2a -= ch[2][PD(lo0)]; s2b -= ch[3][PD(lo0)];
        }
        float s1c = ch[0][PD(hi1)], s1d = ch[1][PD(hi1)];
        float s2c = ch[2][PD(hi1)], s2d = ch[3][PD(hi1)];
        if (lo1 >= 0) {
            s1c -= ch[0][PD(lo1)]; s1d -= ch[1][PD(lo1)];
            s2c -= ch[2][PD(lo1)]; s2d -= ch[3][PD(lo1)];
        }
        float4 ov = orow[jj];
        float c1, c2, var;
        float4 r;
        c1 = SCALEV * s1a; c2 = SCALEV * s2a; var = c2 - c1 * c1;
        r.x = ov.x / (sqrtf(fmaxf(var, 0.f)) + EPSV);
        c1 = SCALEV * s1b; c2 = SCALEV * s2b; var = c2 - c1 * c1;
        r.y = ov.y / (sqrtf(fmaxf(var, 0.f)) + EPSV);
        c1 = SCALEV * s1c; c2 = SCALEV * s2c; var = c2 - c1 * c1;
        r.z = ov.z / (sqrtf(fmaxf(var, 0.f)) + EPSV);
        c1 = SCALEV * s1d; c2 = SCALEV * s2d; var = c2 - c1 * c1;
        r.w = ov.w / (sqrtf(fmaxf(var, 0.f)) + EPSV);
        orow[jj] = r;
    }
}

extern "C" void kernel_launch(void* const* d_in, const int* in_sizes, int n_in,
                              void* d_out, int out_size, void* d_ws, size_t ws_size,
                              hipStream_t stream) {
    const float* x = (const float*)d_in[0];
    float* out = (float*)d_out;
    unsigned* V1 = (unsigned*)d_ws;               // 32 MB bf16-packed vbox(x)
    unsigned* Z1 = V1 + (size_t)NB * IMGSZ / 2;   // 32 MB bf16 V(out)
    unsigned* Z2 = Z1 + (size_t)NB * IMGSZ / 2;   // 32 MB bf16 V(out^2)

    int vgrid = (NCOL2 * VNSEG) / 256;            // 1024 blocks
    vbox_kernel<<<vgrid, 256, 0, stream>>>(x, V1);
    hbox_sub_kernel<<<NB * HH, 256, 0, stream>>>(V1, x, out);
    vbox2_kernel<<<vgrid, 256, 0, stream>>>(out, Z1, Z2);
    hbox_final_kernel<<<NB * HH, 256, 0, stream>>>(Z1, Z2, out);
}

// Round 6
// 213.945 us; speedup vs baseline: 1.2308x; 1.0234x over previous
//
#include <hip/hip_runtime.h>
#include <math.h>

// Problem constants (fixed by setup_inputs): x is (8,1024,1024,2) fp32, k=61
#define NB 8
#define HH 1024
#define WW 1024
#define RAD 30
#define KS 61
#define ROWSZ 2048             /* floats per row (1024 px x 2 ch) */
#define IMGSZ (HH * ROWSZ)
#define STR2 1024              /* float2 per row */
#define NCOL2 (NB * STR2)      /* 8192 float2 columns */
#define VSEGH 64
#define VNSEG (HH / VSEGH)     /* 16 */
#define EPSV 1e-7f
#define SCALEV (1.0f / (float)(KS * KS * 2))
#define PDW (WW + WW / 8)
#define PD(i) ((i) + ((i) >> 3))

// ---- bf16 pack/unpack (manual, round-to-nearest-even) ----------------------
__device__ __forceinline__ unsigned bf16_rn(float f) {
    unsigned u = __float_as_uint(f);
    return (u + 0x7FFFu + ((u >> 16) & 1u)) >> 16;
}
__device__ __forceinline__ unsigned pk2(float a, float b) {
    return bf16_rn(a) | (bf16_rn(b) << 16);
}
__device__ __forceinline__ float2 up2(unsigned u) {
    return make_float2(__uint_as_float(u << 16),
                       __uint_as_float(u & 0xFFFF0000u));
}

__device__ __forceinline__ float2 f2add(float2 a, float2 b) {
    return make_float2(a.x + b.x, a.y + b.y);
}
__device__ __forceinline__ float2 f2sub(float2 a, float2 b) {
    return make_float2(a.x - b.x, a.y - b.y);
}

// ---------------------------------------------------------------------------
// K1: vertical 61-tap box-sum of x -> V1 (bf16-packed). float2 columns,
// VSEGH=64 rows/seg, 512 blocks. Interior path: 16-load batch pinned ahead of
// the consume phase by sched_barrier(0) -> 8KB/wave in flight.
__global__ __launch_bounds__(256, 2) void vbox_kernel(const float* __restrict__ in,
                                                      unsigned* __restrict__ out) {
    int tid = blockIdx.x * 256 + threadIdx.x;
    int col = tid & (NCOL2 - 1);
    int seg = tid >> 13;
    int n = col >> 10;
    int w2 = col & (STR2 - 1);
    const float2* ip = (const float2*)(in + (size_t)n * IMGSZ) + w2;
    unsigned* op = out + (size_t)n * (IMGSZ / 2) + w2;
    int h0 = seg * VSEGH;
    float2 S = make_float2(0.f, 0.f);
    int lo = h0 - RAD; if (lo < 0) lo = 0;
    int h = lo;
    for (; h + 8 <= h0 + RAD; h += 8) {
        float2 W[8];
        #pragma unroll
        for (int i = 0; i < 8; ++i) W[i] = ip[(h + i) * STR2];
        __builtin_amdgcn_sched_barrier(0);
        #pragma unroll
        for (int i = 0; i < 8; ++i) S = f2add(S, W[i]);
    }
    for (; h < h0 + RAD; ++h) S = f2add(S, ip[h * STR2]);

    if (seg != 0 && seg != VNSEG - 1) {
        const float2* lp = ip + (h0 + RAD) * STR2;
        const float2* tp = ip + (h0 - RAD) * STR2;
        unsigned* opp = op + (size_t)h0 * STR2;
        for (int r = 0; r < VSEGH; r += 8) {
            float2 L[8], T[8];
            #pragma unroll
            for (int i = 0; i < 8; ++i) L[i] = lp[(r + i) * STR2];
            #pragma unroll
            for (int i = 0; i < 8; ++i) T[i] = tp[(r + i) * STR2];
            __builtin_amdgcn_sched_barrier(0);
            #pragma unroll
            for (int i = 0; i < 8; ++i) {
                S = f2add(S, L[i]);
                opp[(r + i) * STR2] = pk2(S.x, S.y);
                S = f2sub(S, T[i]);
            }
        }
    } else {
        const float2 Z = make_float2(0.f, 0.f);
        for (int ho = h0; ho < h0 + VSEGH; ho += 4) {
            float2 a[4], b[4];
            #pragma unroll
            for (int i = 0; i < 4; ++i) {
                int ha = ho + i + RAD;
                a[i] = (ha < HH) ? ip[ha * STR2] : Z;
            }
            #pragma unroll
            for (int i = 0; i < 4; ++i) {
                int hb = ho + i - RAD;
                b[i] = (hb >= 0) ? ip[hb * STR2] : Z;
            }
            #pragma unroll
            for (int i = 0; i < 4; ++i) {
                S = f2add(S, a[i]);
                op[(size_t)(ho + i) * STR2] = pk2(S.x, S.y);
                S = f2sub(S, b[i]);
            }
        }
    }
}

// ---------------------------------------------------------------------------
// K3: vertical dual box-sum of out and out^2 -> Z1, Z2 (bf16-packed).
__global__ __launch_bounds__(256, 2) void vbox2_kernel(const float* __restrict__ in,
                                                       unsigned* __restrict__ o1,
                                                       unsigned* __restrict__ o2) {
    int tid = blockIdx.x * 256 + threadIdx.x;
    int col = tid & (NCOL2 - 1);
    int seg = tid >> 13;
    int n = col >> 10;
    int w2 = col & (STR2 - 1);
    const float2* ip = (const float2*)(in + (size_t)n * IMGSZ) + w2;
    unsigned* p1 = o1 + (size_t)n * (IMGSZ / 2) + w2;
    unsigned* p2 = o2 + (size_t)n * (IMGSZ / 2) + w2;
    int h0 = seg * VSEGH;
    float2 S = make_float2(0.f, 0.f);
    float2 Q = make_float2(0.f, 0.f);
    int lo = h0 - RAD; if (lo < 0) lo = 0;
    int h = lo;
    for (; h + 8 <= h0 + RAD; h += 8) {
        float2 W[8];
        #pragma unroll
        for (int i = 0; i < 8; ++i) W[i] = ip[(h + i) * STR2];
        __builtin_amdgcn_sched_barrier(0);
        #pragma unroll
        for (int i = 0; i < 8; ++i) {
            S = f2add(S, W[i]);
            Q.x = fmaf(W[i].x, W[i].x, Q.x);
            Q.y = fmaf(W[i].y, W[i].y, Q.y);
        }
    }
    for (; h < h0 + RAD; ++h) {
        float2 v = ip[h * STR2];
        S = f2add(S, v);
        Q.x = fmaf(v.x, v.x, Q.x); Q.y = fmaf(v.y, v.y, Q.y);
    }

    if (seg != 0 && seg != VNSEG - 1) {
        const float2* lp = ip + (h0 + RAD) * STR2;
        const float2* tp = ip + (h0 - RAD) * STR2;
        unsigned* q1 = p1 + (size_t)h0 * STR2;
        unsigned* q2 = p2 + (size_t)h0 * STR2;
        for (int r = 0; r < VSEGH; r += 8) {
            float2 L[8], T[8];
            #pragma unroll
            for (int i = 0; i < 8; ++i) L[i] = lp[(r + i) * STR2];
            #pragma unroll
            for (int i = 0; i < 8; ++i) T[i] = tp[(r + i) * STR2];
            __builtin_amdgcn_sched_barrier(0);
            #pragma unroll
            for (int i = 0; i < 8; ++i) {
                S = f2add(S, L[i]);
                Q.x = fmaf(L[i].x, L[i].x, Q.x);
                Q.y = fmaf(L[i].y, L[i].y, Q.y);
                q1[(r + i) * STR2] = pk2(S.x, S.y);
                q2[(r + i) * STR2] = pk2(Q.x, Q.y);
                S = f2sub(S, T[i]);
                Q.x = fmaf(-T[i].x, T[i].x, Q.x);
                Q.y = fmaf(-T[i].y, T[i].y, Q.y);
            }
        }
    } else {
        const float2 Z = make_float2(0.f, 0.f);
        for (int ho = h0; ho < h0 + VSEGH; ho += 4) {
            float2 a[4], b[4];
            #pragma unroll
            for (int i = 0; i < 4; ++i) {
                int ha = ho + i + RAD;
                a[i] = (ha < HH) ? ip[ha * STR2] : Z;
            }
            #pragma unroll
            for (int i = 0; i < 4; ++i) {
                int hb = ho + i - RAD;
                b[i] = (hb >= 0) ? ip[hb * STR2] : Z;
            }
            #pragma unroll
            for (int i = 0; i < 4; ++i) {
                S = f2add(S, a[i]);
                Q.x = fmaf(a[i].x, a[i].x, Q.x);
                Q.y = fmaf(a[i].y, a[i].y, Q.y);
                p1[(size_t)(ho + i) * STR2] = pk2(S.x, S.y);
                p2[(size_t)(ho + i) * STR2] = pk2(Q.x, Q.y);
                S = f2sub(S, b[i]);
                Q.x = fmaf(-b[i].x, b[i].x, Q.x);
                Q.y = fmaf(-b[i].y, b[i].y, Q.y);
            }
        }
    }
}

__device__ inline float wave_incl_scan(float v) {
    int lane = threadIdx.x & 63;
    #pragma unroll
    for (int d = 1; d < 64; d <<= 1) {
        float o = __shfl_up(v, d, 64);
        if (lane >= d) v += o;
    }
    return v;
}

// ---------------------------------------------------------------------------
// K2: horizontal box of V1 (bf16 in) per row + out = x - s*box. One block/row.
__global__ __launch_bounds__(256) void hbox_sub_kernel(const unsigned* __restrict__ vsum,
                                                       const float* __restrict__ x,
                                                       float* __restrict__ out) {
    __shared__ float ch[2][PDW];
    __shared__ float wtot[4];
    int t = threadIdx.x;
    size_t g = (size_t)blockIdx.x * ROWSZ;
    const uint4* vrow = (const uint4*)(vsum + (size_t)blockIdx.x * STR2);
    uint4 u = vrow[t];   // 4 pixels x 2 ch
    {
        float2 p0 = up2(u.x), p1 = up2(u.y), p2 = up2(u.z), p3 = up2(u.w);
        int w = 4 * t;
        ch[0][PD(w + 0)] = p0.x; ch[1][PD(w + 0)] = p0.y;
        ch[0][PD(w + 1)] = p1.x; ch[1][PD(w + 1)] = p1.y;
        ch[0][PD(w + 2)] = p2.x; ch[1][PD(w + 2)] = p2.y;
        ch[0][PD(w + 3)] = p3.x; ch[1][PD(w + 3)] = p3.y;
    }
    __syncthreads();
    // prefix: 2 waves per channel, per-thread chunk of 8
    {
        int c = t >> 7, j = t & 127, base = j * 8;
        float v[8]; float run = 0.f;
        #pragma unroll
        for (int i = 0; i < 8; ++i) { run += ch[c][PD(base + i)]; v[i] = run; }
        float incl = wave_incl_scan(run);
        int wid = t >> 6;
        if ((t & 63) == 63) wtot[wid] = incl;
        __syncthreads();
        float off = incl - run;
        if (wid & 1) off += wtot[wid - 1];
        #pragma unroll
        for (int i = 0; i < 8; ++i) ch[c][PD(base + i)] = off + v[i];
    }
    __syncthreads();
    const float4* xrow = (const float4*)(x + g);
    float4* orow = (float4*)(out + g);
    #pragma unroll
    for (int i = 0; i < 2; ++i) {
        int jj = t + 256 * i;
        int w0 = 2 * jj, w1 = 2 * jj + 1;
        int hi0 = w0 + RAD; if (hi0 > WW - 1) hi0 = WW - 1;
        int hi1 = w1 + RAD; if (hi1 > WW - 1) hi1 = WW - 1;
        int lo0 = w0 - RAD - 1, lo1 = w1 - RAD - 1;
        float s00 = ch[0][PD(hi0)], s10 = ch[1][PD(hi0)];
        if (lo0 >= 0) { s00 -= ch[0][PD(lo0)]; s10 -= ch[1][PD(lo0)]; }
        float s01 = ch[0][PD(hi1)], s11 = ch[1][PD(hi1)];
        if (lo1 >= 0) { s01 -= ch[0][PD(lo1)]; s11 -= ch[1][PD(lo1)]; }
        float4 xv = xrow[jj];
        float4 o;
        o.x = xv.x - SCALEV * s00; o.y = xv.y - SCALEV * s10;
        o.z = xv.z - SCALEV * s01; o.w = xv.w - SCALEV * s11;
        orow[jj] = o;
    }
}

// ---------------------------------------------------------------------------
// K4: horizontal box of Z1,Z2 (bf16 in) + finalize y = out/(sqrt(c2-c1^2)+eps).
__global__ __launch_bounds__(256) void hbox_final_kernel(const unsigned* __restrict__ z1,
                                                         const unsigned* __restrict__ z2,
                                                         float* __restrict__ out) {
    __shared__ float ch[4][PDW];
    int t = threadIdx.x;
    size_t g = (size_t)blockIdx.x * ROWSZ;
    const uint4* arow = (const uint4*)(z1 + (size_t)blockIdx.x * STR2);
    const uint4* brow = (const uint4*)(z2 + (size_t)blockIdx.x * STR2);
    uint4 ua = arow[t], ub = brow[t];
    {
        float2 p0 = up2(ua.x), p1 = up2(ua.y), p2 = up2(ua.z), p3 = up2(ua.w);
        float2 q0 = up2(ub.x), q1 = up2(ub.y), q2 = up2(ub.z), q3 = up2(ub.w);
        int w = 4 * t;
        ch[0][PD(w + 0)] = p0.x; ch[1][PD(w + 0)] = p0.y;
        ch[0][PD(w + 1)] = p1.x; ch[1][PD(w + 1)] = p1.y;
        ch[0][PD(w + 2)] = p2.x; ch[1][PD(w + 2)] = p2.y;
        ch[0][PD(w + 3)] = p3.x; ch[1][PD(w + 3)] = p3.y;
        ch[2][PD(w + 0)] = q0.x; ch[3][PD(w + 0)] = q0.y;
        ch[2][PD(w + 1)] = q1.x; ch[3][PD(w + 1)] = q1.y;
        ch[2][PD(w + 2)] = q2.x; ch[3][PD(w + 2)] = q2.y;
        ch[2][PD(w + 3)] = q3.x; ch[3][PD(w + 3)] = q3.y;
    }
    __syncthreads();
    // prefix: 4 arrays, 1 wave each, chunk 16
    {
        int a = t >> 6, j = t & 63, base = j * 16;
        float v[16]; float run = 0.f;
        #pragma unroll
        for (int i = 0; i < 16; ++i) { run += ch[a][PD(base + i)]; v[i] = run; }
        float incl = wave_incl_scan(run);
        float off = incl - run;
        #pragma unroll
        for (int i = 0; i < 16; ++i) ch[a][PD(base + i)] = off + v[i];
    }
    __syncthreads();
    float4* orow = (float4*)(out + g);
    #pragma unroll
    for (int i = 0; i < 2; ++i) {
        int jj = t + 256 * i;
        int w0 = 2 * jj, w1 = 2 * jj + 1;
        int hi0 = w0 + RAD; if (hi0 > WW - 1) hi0 = WW - 1;
        int hi1 = w1 + RAD; if (hi1 > WW - 1) hi1 = WW - 1;
        int lo0 = w0 - RAD - 1, lo1 = w1 - RAD - 1;
        float s1a = ch[0][PD(hi0)], s1b = ch[1][PD(hi0)];
        float s2a = ch[2][PD(hi0)], s2b = ch[3][PD(hi0)];
        if (lo0 >= 0) {
            s1a -= ch[0][PD(lo0)]; s1b -= ch[1][PD(lo0)];
            s2a -= ch[2][PD(lo0)]; s2b -= ch[3][PD(lo0)];
        }
        float s1c = ch[0][PD(hi1)], s1d = ch[1][PD(hi1)];
        float s2c = ch[2][PD(hi1)], s2d = ch[3][PD(hi1)];
        if (lo1 >= 0) {
            s1c -= ch[0][PD(lo1)]; s1d -= ch[1][PD(lo1)];
            s2c -= ch[2][PD(lo1)]; s2d -= ch[3][PD(lo1)];
        }
        float4 ov = orow[jj];
        float c1, c2, var;
        float4 r;
        c1 = SCALEV * s1a; c2 = SCALEV * s2a; var = c2 - c1 * c1;
        r.x = ov.x / (sqrtf(fmaxf(var, 0.f)) + EPSV);
        c1 = SCALEV * s1b; c2 = SCALEV * s2b; var = c2 - c1 * c1;
        r.y = ov.y / (sqrtf(fmaxf(var, 0.f)) + EPSV);
        c1 = SCALEV * s1c; c2 = SCALEV * s2c; var = c2 - c1 * c1;
        r.z = ov.z / (sqrtf(fmaxf(var, 0.f)) + EPSV);
        c1 = SCALEV * s1d; c2 = SCALEV * s2d; var = c2 - c1 * c1;
        r.w = ov.w / (sqrtf(fmaxf(var, 0.f)) + EPSV);
        orow[jj] = r;
    }
}

extern "C" void kernel_launch(void* const* d_in, const int* in_sizes, int n_in,
                              void* d_out, int out_size, void* d_ws, size_t ws_size,
                              hipStream_t stream) {
    const float* x = (const float*)d_in[0];
    float* out = (float*)d_out;
    unsigned* V1 = (unsigned*)d_ws;               // 32 MB bf16-packed vbox(x)
    unsigned* Z1 = V1 + (size_t)NB * IMGSZ / 2;   // 32 MB bf16 V(out)
    unsigned* Z2 = Z1 + (size_t)NB * IMGSZ / 2;   // 32 MB bf16 V(out^2)

    int vgrid = (NCOL2 * VNSEG) / 256;            // 512 blocks
    vbox_kernel<<<vgrid, 256, 0, stream>>>(x, V1);
    hbox_sub_kernel<<<NB * HH, 256, 0, stream>>>(V1, x, out);
    vbox2_kernel<<<vgrid, 256, 0, stream>>>(out, Z1, Z2);
    hbox_final_kernel<<<NB * HH, 256, 0, stream>>>(Z1, Z2, out);
}